// Round 13
// baseline (143.283 us; speedup 1.0000x reference)
//
#include <hip/hip_runtime.h>
#include <stdint.h>

#define B_ 4
#define S_ 2048
#define E_ 1024
#define H_ 16
#define D_ 64
#define M_ (B_*S_)   // 8192

typedef unsigned short u16;
typedef __bf16 bf16x8 __attribute__((ext_vector_type(8)));
typedef __bf16 bf16x4 __attribute__((ext_vector_type(4)));
typedef float f32x4 __attribute__((ext_vector_type(4)));
typedef u16 u16x8 __attribute__((ext_vector_type(8)));

#define GLD16(g, l) __builtin_amdgcn_global_load_lds((const __attribute__((address_space(1))) void*)(g), (__attribute__((address_space(3))) void*)(l), 16, 0, 0)

__device__ inline float fexp2(float x) {
#if __has_builtin(__builtin_amdgcn_exp2f)
  return __builtin_amdgcn_exp2f(x);
#else
  return exp2f(x);
#endif
}

__device__ inline u16 f2bf(float f) {
  union { __bf16 b; u16 u; } cv; cv.b = (__bf16)f; return cv.u;
}

// ---------------- all converts in one launch ----------------
__device__ inline void cvt8(const float* __restrict__ src, u16* __restrict__ dst, int i) {
  float4 a = *(const float4*)(src + i);
  float4 b = *(const float4*)(src + i + 4);
  u16x8 o;
  o[0]=f2bf(a.x); o[1]=f2bf(a.y); o[2]=f2bf(a.z); o[3]=f2bf(a.w);
  o[4]=f2bf(b.x); o[5]=f2bf(b.y); o[6]=f2bf(b.z); o[7]=f2bf(b.w);
  *(u16x8*)(dst + i) = o;
}

// blocks: [0,4096) X | [4096,5632) Wq/Wk/Wv (512 each) | [5632,5664) pad
__global__ void cvt_all(const float* __restrict__ X, const float* __restrict__ Wq,
                        const float* __restrict__ Wk, const float* __restrict__ Wv,
                        const int* __restrict__ pad,
                        u16* __restrict__ Xb, u16* __restrict__ Wb,
                        float* __restrict__ padf, u16* __restrict__ padb16) {
  const int bi = blockIdx.x;
  if (bi < 4096) {
    cvt8(X, Xb, bi*2048 + threadIdx.x*8);
  } else if (bi < 5632) {
    int r = bi - 4096;
    int mat = r >> 9, j = r & 511;
    const float* src = (mat == 0) ? Wq : (mat == 1) ? Wk : Wv;
    cvt8(src, Wb + (size_t)mat*E_*E_, j*2048 + threadIdx.x*8);
  } else {
    int i = (bi - 5632)*256 + threadIdx.x;
    float p = (float)pad[i];
    padf[i] = p;
    padb16[i] = f2bf(p);
  }
}

// ---------------- fused QKV projection GEMM (unchanged) ----------------
__launch_bounds__(512)
__global__ void qkv_gemm3(const u16* __restrict__ A, const u16* __restrict__ Wall,
                          const float* __restrict__ bq, const float* __restrict__ bk,
                          const float* __restrict__ bv, const float* __restrict__ padf,
                          u16* __restrict__ Qb, u16* __restrict__ Kb, u16* __restrict__ Vtb,
                          float qscale) {
  __shared__ __align__(16) u16 As[3*256*64];   // 96 KB
  __shared__ __align__(16) u16 Bs[3*128*64];   // 48 KB
  const int t = threadIdx.x;        // 0..511
  const int lane = t & 63;
  const int w = t >> 6;             // wave 0..7
  const int wr = w >> 1, wc = w & 1;
  const int l15 = lane & 15, lhi = lane >> 4;
  const int l = blockIdx.x;
  const int xcd = l & 7, s = l >> 3;
  const int mat = s >> 5, inner = s & 31;
  const int m0 = (xcd*4 + (inner & 3)) * 256;
  const int n0 = (inner >> 2) * 128;
  const u16* W = Wall + (size_t)mat*E_*E_;
  const float* bias = (mat == 0) ? bq : (mat == 1) ? bk : bv;
  u16* out = (mat == 0) ? Qb : (mat == 1) ? Kb : Vtb;
  const float scale = (mat == 0) ? qscale : 1.0f;
  const int mode = (mat == 2);

  f32x4 acc[4][4] = {};

  const int rA = t >> 3;
  const int cbs = ((t & 7) ^ ((t >> 3) & 7)) * 8;
  const u16* Asrc = A + (size_t)(m0 + rA)*E_ + cbs;
  const u16* Wsrc = W + (size_t)(n0 + rA)*E_ + cbs;

  auto stage = [&](int bufi, int k0) {
#pragma unroll
    for (int c = 0; c < 4; ++c)
      GLD16(Asrc + (size_t)(c*64)*E_ + k0, As + bufi*16384 + c*4096 + t*8);
#pragma unroll
    for (int c = 0; c < 2; ++c)
      GLD16(Wsrc + (size_t)(c*64)*E_ + k0, Bs + bufi*8192 + c*4096 + t*8);
  };

  stage(0, 0);
  stage(1, 64);
  const int fkey = l15 & 7;
  const int arow = wr*64, brow = wc*64;
  int cur = 0, nxt = 1, nn = 2;
  for (int kt = 0; kt < 16; ++kt) {
    if (kt < 15) { asm volatile("s_waitcnt vmcnt(6)" ::: "memory"); }
    else         { asm volatile("s_waitcnt vmcnt(0)" ::: "memory"); }
    __builtin_amdgcn_s_barrier();
    __builtin_amdgcn_sched_barrier(0);
    const u16* Ab = As + cur*16384;
    const u16* Bb = Bs + cur*8192;
    bf16x8 af[4], bfr[4];
#pragma unroll
    for (int i = 0; i < 4; ++i)
      af[i] = *(const bf16x8*)&Ab[(arow + i*16 + l15)*64 + ((lhi) ^ fkey)*8];
#pragma unroll
    for (int i = 0; i < 4; ++i)
      bfr[i] = *(const bf16x8*)&Bb[(brow + i*16 + l15)*64 + ((lhi) ^ fkey)*8];
    if (kt + 2 < 16) stage(nn, (kt+2)*64);
    __builtin_amdgcn_s_setprio(1);
#pragma unroll
    for (int mi = 0; mi < 4; ++mi)
#pragma unroll
      for (int ni = 0; ni < 4; ++ni)
        acc[mi][ni] = __builtin_amdgcn_mfma_f32_16x16x32_bf16(af[mi], bfr[ni], acc[mi][ni], 0, 0, 0);
    __builtin_amdgcn_s_setprio(0);
#pragma unroll
    for (int i = 0; i < 4; ++i)
      af[i] = *(const bf16x8*)&Ab[(arow + i*16 + l15)*64 + ((4 + lhi) ^ fkey)*8];
#pragma unroll
    for (int i = 0; i < 4; ++i)
      bfr[i] = *(const bf16x8*)&Bb[(brow + i*16 + l15)*64 + ((4 + lhi) ^ fkey)*8];
    __builtin_amdgcn_s_setprio(1);
#pragma unroll
    for (int mi = 0; mi < 4; ++mi)
#pragma unroll
      for (int ni = 0; ni < 4; ++ni)
        acc[mi][ni] = __builtin_amdgcn_mfma_f32_16x16x32_bf16(af[mi], bfr[ni], acc[mi][ni], 0, 0, 0);
    __builtin_amdgcn_s_setprio(0);
    int tmp = cur; cur = nxt; nxt = nn; nn = tmp;
  }

#pragma unroll
  for (int mi = 0; mi < 4; ++mi) {
#pragma unroll
    for (int ni = 0; ni < 4; ++ni) {
      int n = n0 + wc*64 + ni*16 + l15;
      float bia = bias[n];
      int h = n >> 6, d = n & 63;
      if (mode == 0) {
#pragma unroll
        for (int j = 0; j < 4; ++j) {
          int m = m0 + wr*64 + mi*16 + lhi*4 + j;
          int b = m >> 11, sq = m & 2047;
          out[((size_t)((b*H_ + h)*S_ + sq))*D_ + d] = f2bf((acc[mi][ni][j] + bia) * scale);
        }
      } else {
        int m = m0 + wr*64 + mi*16 + lhi*4;
        int b = m >> 11, sq = m & 2047;
        float4 pv = *(const float4*)(padf + b*S_ + sq);   // zero padded V rows
        u16 pk0 = f2bf((acc[mi][ni][0] + bia) * pv.x);
        u16 pk1 = f2bf((acc[mi][ni][1] + bia) * pv.y);
        u16 pk2 = f2bf((acc[mi][ni][2] + bia) * pv.z);
        u16 pk3 = f2bf((acc[mi][ni][3] + bia) * pv.w);
        u16* p = &out[((size_t)((b*H_ + h)*D_ + d))*S_ + sq];
        p[0]=pk0; p[1]=pk1; p[2]=pk2; p[3]=pk3;
      }
    }
  }
}

// ---------------- fused causal+pad flash attention (ILP2: 4 waves x 2 q-subtiles) ----------------
// Q,K: [BH][S][D] bf16 (Q pre-scaled by log2e/sqrt(D)); Vt: [BH][D][S] bf16,
// V rows pre-zeroed at padded kv. Grid 512 x 256 thr. Paired halves (qt,15-qt).
// Each wave owns q rows {q0+w*16, q0+64+w*16}: two independent softmax chains
// sharing K/V/pad fragment reads; both walk kv tiles from 0 in lockstep.
// Stream A skips the final (fully-masked) tile; each stream masks only its
// own diagonal tile.
#define QB 128
#define KB 64
#define NQT (S_/QB)   // 16
__launch_bounds__(256, 2)
__global__ void attn(const u16* __restrict__ Q, const u16* __restrict__ Kg,
                     const u16* __restrict__ Vt, const float* __restrict__ padf,
                     const u16* __restrict__ padb16, float* __restrict__ out) {
  __shared__ __align__(16) u16 Ks[2*4096];    // 2 x [64 kv][64 d], swizzled
  __shared__ __align__(16) u16 Vs[2*4096];    // 2 x [64 d][64 kv], swizzled
  __shared__ __align__(16) u16 Ps[8*1024];    // per (wave,stream) P [16 q][64 kv]
  const int t = threadIdx.x, lane = t & 63, w = t >> 6;   // w 0..3
  const int l15 = lane & 15, lhi = lane >> 4;
  const int l = blockIdx.x;                   // 512 blocks
  const int bh = (l & 7) + 8 * (l >> 6);
  const int xt = (l >> 3) & 7;                // q-tile pair index 0..7
  const int b = bh >> 4, h = bh & 15;
  const int lsw = ((lane >> 3) & 7) << 3;     // staging swizzle (elem units)
  const int key = l15 & 7;
  const int x0 = ((0 + lhi) ^ key) * 8;       // K/V fragment col offsets (elems)
  const int x1 = ((4 + lhi) ^ key) * 8;
  const int pxk = key << 4;
  const int pwA = (w*2    )*1024 + l15*64;
  const int pwB = (w*2 + 1)*1024 + l15*64;
  int pwrA[4], pwrB[4];
#pragma unroll
  for (int f = 0; f < 4; ++f) {
    int off = ((f*32 + lhi*8) ^ pxk) >> 1;
    pwrA[f] = pwA + off;
    pwrB[f] = pwB + off;
  }
  const int prd0 = ((      lhi*16) ^ pxk) >> 1;
  const int prd1 = ((64 +  lhi*16) ^ pxk) >> 1;

  const float* padb = padf + b*S_;
  const u16* padkb = padb16 + b*S_ + lhi*8;   // pad B-fragment base

  const int leo = (t*8) ^ lsw;                // elem offset in [0,2048)
  const u16* Kls = Kg + (size_t)bh*S_*D_ + leo;
  const u16* Vls = Vt + (size_t)bh*D_*S_ + (size_t)(leo >> 6)*S_ + (leo & 63);
  u16* KsD = Ks + t*8;
  u16* VsD = Vs + t*8;

  auto stage = [&](int bufi, int kv0) {
    GLD16(Kls + (size_t)kv0*D_,        KsD + bufi*4096);
    GLD16(Kls + (size_t)kv0*D_ + 2048, KsD + bufi*4096 + 2048);
    GLD16(Vls + kv0,                   VsD + bufi*4096);
    GLD16(Vls + kv0 + (size_t)32*S_,   VsD + bufi*4096 + 2048);
  };

  for (int half = 0; half < 2; ++half) {
    const int qt = half ? (NQT - 1 - xt) : xt;
    const int q0 = qt * QB;
    const int nkt = 2*(qt + 1);

    const u16* QrA = Q + (size_t)(bh*S_ + q0 + w*16 + l15)*D_;
    const u16* QrB = QrA + (size_t)64*D_;
    bf16x8 qaA0 = *(const bf16x8*)(QrA + lhi*8);
    bf16x8 qaA1 = *(const bf16x8*)(QrA + 32 + lhi*8);
    bf16x8 qaB0 = *(const bf16x8*)(QrB + lhi*8);
    bf16x8 qaB1 = *(const bf16x8*)(QrB + 32 + lhi*8);

    f32x4 oA[4] = {}, oB[4] = {};
    f32x4 lsA = {}, lsB = {};
    float mA = -1e30f, mB = -1e30f;

    stage(0, 0);
    __syncthreads();
    for (int kt = 0; kt < nkt; ++kt) {
      if (kt + 1 < nkt) stage((kt+1)&1, (kt+1)*KB);
      const u16* Kb_ = Ks + (kt&1)*4096;
      const u16* Vb_ = Vs + (kt&1)*4096;
      const int kv0 = kt*KB;
      const bool aAct = (kt < nkt - 1);   // A's last tile is fully masked: skip

      // shared K fragments
      bf16x8 kf0[4], kf1[4];
#pragma unroll
      for (int f = 0; f < 4; ++f) {
        const u16* kr = Kb_ + (f*16 + l15)*64;
        kf0[f] = *(const bf16x8*)(kr + x0);
        kf1[f] = *(const bf16x8*)(kr + x1);
      }
      f32x4 scA[4], scB[4];
      __builtin_amdgcn_s_setprio(1);
#pragma unroll
      for (int f = 0; f < 4; ++f) {
        f32x4 z = {};
        z = __builtin_amdgcn_mfma_f32_16x16x32_bf16(kf0[f], qaB0, z, 0, 0, 0);
        z = __builtin_amdgcn_mfma_f32_16x16x32_bf16(kf1[f], qaB1, z, 0, 0, 0);
        scB[f] = z;
      }
      if (aAct) {
#pragma unroll
        for (int f = 0; f < 4; ++f) {
          f32x4 z = {};
          z = __builtin_amdgcn_mfma_f32_16x16x32_bf16(kf0[f], qaA0, z, 0, 0, 0);
          z = __builtin_amdgcn_mfma_f32_16x16x32_bf16(kf1[f], qaA1, z, 0, 0, 0);
          scA[f] = z;
        }
      }
      __builtin_amdgcn_s_setprio(0);
      // diagonal masks (rel = w*16+l15 for each stream's own diagonal tile)
      const int rel = w*16 + l15;
      if (kt == nkt - 1) {               // B diagonal
#pragma unroll
        for (int f = 0; f < 4; ++f)
#pragma unroll
          for (int j = 0; j < 4; ++j)
            if (f*16 + lhi*4 + j > rel) scB[f][j] = -1e30f;
      }
      if (aAct && kt == nkt - 2) {       // A diagonal
#pragma unroll
        for (int f = 0; f < 4; ++f)
#pragma unroll
          for (int j = 0; j < 4; ++j)
            if (f*16 + lhi*4 + j > rel) scA[f][j] = -1e30f;
      }

      // softmax per stream (independent chains)
      auto softmax = [&](f32x4* sc, f32x4* o, f32x4& ls, float& mrow, const int* pwr) {
        float mx0 = fmaxf(fmaxf(sc[0][0], sc[0][1]), fmaxf(sc[0][2], sc[0][3]));
        float mx1 = fmaxf(fmaxf(sc[1][0], sc[1][1]), fmaxf(sc[1][2], sc[1][3]));
        float mx2 = fmaxf(fmaxf(sc[2][0], sc[2][1]), fmaxf(sc[2][2], sc[2][3]));
        float mx3 = fmaxf(fmaxf(sc[3][0], sc[3][1]), fmaxf(sc[3][2], sc[3][3]));
        float pmax = fmaxf(fmaxf(mx0, mx1), fmaxf(mx2, mx3));
        pmax = fmaxf(pmax, __shfl_xor(pmax, 16));
        pmax = fmaxf(pmax, __shfl_xor(pmax, 32));
        if (__any(pmax > mrow + 8.0f)) {
          float mnew = fmaxf(mrow, pmax);
          float corr = fexp2(mrow - mnew);
          mrow = mnew;
          float cr[4];
#pragma unroll
          for (int j = 0; j < 4; ++j) cr[j] = __shfl(corr, lhi*4 + j);
#pragma unroll
          for (int df = 0; df < 4; ++df)
#pragma unroll
            for (int j = 0; j < 4; ++j) o[df][j] *= cr[j];
#pragma unroll
          for (int j = 0; j < 4; ++j) ls[j] *= cr[j];
        }
#pragma unroll
        for (int f = 0; f < 4; ++f) {
          bf16x4 pk;
          pk[0] = (__bf16)fexp2(sc[f][0] - mrow);
          pk[1] = (__bf16)fexp2(sc[f][1] - mrow);
          pk[2] = (__bf16)fexp2(sc[f][2] - mrow);
          pk[3] = (__bf16)fexp2(sc[f][3] - mrow);
          *(bf16x4*)(Ps + pwr[f]) = pk;
        }
      };
      softmax(scB, oB, lsB, mB, pwrB);
      if (aAct) softmax(scA, oA, lsA, mA, pwrA);

      // shared pad fragments; per-stream P fragments
      bf16x8 pf0 = *(const bf16x8*)(padkb + kv0);
      bf16x8 pf1 = *(const bf16x8*)(padkb + kv0 + 32);
      bf16x8 paB0 = *(const bf16x8*)(Ps + pwB + prd0);
      bf16x8 paB1 = *(const bf16x8*)(Ps + pwB + prd1);
      bf16x8 paA0, paA1;
      if (aAct) {
        paA0 = *(const bf16x8*)(Ps + pwA + prd0);
        paA1 = *(const bf16x8*)(Ps + pwA + prd1);
      }
      __builtin_amdgcn_s_setprio(1);
      lsB = __builtin_amdgcn_mfma_f32_16x16x32_bf16(paB0, pf0, lsB, 0, 0, 0);
      lsB = __builtin_amdgcn_mfma_f32_16x16x32_bf16(paB1, pf1, lsB, 0, 0, 0);
      if (aAct) {
        lsA = __builtin_amdgcn_mfma_f32_16x16x32_bf16(paA0, pf0, lsA, 0, 0, 0);
        lsA = __builtin_amdgcn_mfma_f32_16x16x32_bf16(paA1, pf1, lsA, 0, 0, 0);
      }
#pragma unroll
      for (int df = 0; df < 4; ++df) {
        const u16* vr = Vb_ + (df*16 + l15)*64;
        bf16x8 vr0 = *(const bf16x8*)(vr + x0);
        bf16x8 vr1 = *(const bf16x8*)(vr + x1);
        oB[df] = __builtin_amdgcn_mfma_f32_16x16x32_bf16(paB0, vr0, oB[df], 0, 0, 0);
        oB[df] = __builtin_amdgcn_mfma_f32_16x16x32_bf16(paB1, vr1, oB[df], 0, 0, 0);
        if (aAct) {
          oA[df] = __builtin_amdgcn_mfma_f32_16x16x32_bf16(paA0, vr0, oA[df], 0, 0, 0);
          oA[df] = __builtin_amdgcn_mfma_f32_16x16x32_bf16(paA1, vr1, oA[df], 0, 0, 0);
        }
      }
      __builtin_amdgcn_s_setprio(0);
      __syncthreads();
    }

    // epilogue (both streams)
    auto writeOut = [&](int q0w, f32x4* o, f32x4& ls) {
#pragma unroll
      for (int j = 0; j < 4; ++j) {
        int q = q0w + w*16 + lhi*4 + j;
        float lr = ls[j];
        float pq = padb[q];
        float inv = (lr > 0.f) ? pq / lr : 0.f;
#pragma unroll
        for (int df = 0; df < 4; ++df)
          out[((size_t)(b*S_ + q))*E_ + h*D_ + df*16 + l15] = o[df][j] * inv;
      }
    };
    writeOut(q0,      oA, lsA);
    writeOut(q0 + 64, oB, lsB);
  }
}

extern "C" void kernel_launch(void* const* d_in, const int* in_sizes, int n_in,
                              void* d_out, int out_size, void* d_ws, size_t ws_size,
                              hipStream_t stream) {
  const float* X  = (const float*)d_in[0];
  const int*  pad = (const int*)d_in[1];
  const float* Wq = (const float*)d_in[2];
  const float* bq = (const float*)d_in[3];
  const float* Wk = (const float*)d_in[4];
  const float* bk = (const float*)d_in[5];
  const float* Wv = (const float*)d_in[6];
  const float* bv = (const float*)d_in[7];
  float* out = (float*)d_out;

  u16* Xb  = (u16*)d_ws;                         // 16 MB
  u16* Wb  = Xb + (size_t)M_*E_;                 // 6 MB (3 matrices)
  u16* Qb  = Wb + (size_t)3*E_*E_;               // 16 MB
  u16* Kb  = Qb + (size_t)M_*E_;                 // 16 MB
  u16* Vtb = Kb + (size_t)M_*E_;                 // 16 MB
  float* padfb = (float*)(Vtb + (size_t)M_*E_);  // 32 KB
  u16* padb16 = (u16*)(padfb + B_*S_);           // 16 KB

  cvt_all<<<5664, 256, 0, stream>>>(X, Wq, Wk, Wv, pad, Xb, Wb, padfb, padb16);

  // Q pre-scaled by (1/sqrt(D)) * log2(e) so attention exp is pure exp2
  qkv_gemm3<<<768, 512, 0, stream>>>(Xb, Wb, bq, bk, bv, padfb, Qb, Kb, Vtb, 0.18033688f);

  attn<<<512, 256, 0, stream>>>(Qb, Kb, Vtb, padfb, padb16, out);
}

// Round 14
// 135.199 us; speedup vs baseline: 1.0598x; 1.0598x over previous
//
#include <hip/hip_runtime.h>
#include <stdint.h>

#define B_ 4
#define S_ 2048
#define E_ 1024
#define H_ 16
#define D_ 64
#define M_ (B_*S_)   // 8192

typedef unsigned short u16;
typedef __bf16 bf16x8 __attribute__((ext_vector_type(8)));
typedef __bf16 bf16x4 __attribute__((ext_vector_type(4)));
typedef float f32x4 __attribute__((ext_vector_type(4)));
typedef u16 u16x8 __attribute__((ext_vector_type(8)));

#define GLD16(g, l) __builtin_amdgcn_global_load_lds((const __attribute__((address_space(1))) void*)(g), (__attribute__((address_space(3))) void*)(l), 16, 0, 0)

__device__ inline float fexp2(float x) {
#if __has_builtin(__builtin_amdgcn_exp2f)
  return __builtin_amdgcn_exp2f(x);
#else
  return exp2f(x);
#endif
}

__device__ inline u16 f2bf(float f) {
  union { __bf16 b; u16 u; } cv; cv.b = (__bf16)f; return cv.u;
}

// ---------------- all converts in one launch ----------------
__device__ inline void cvt8(const float* __restrict__ src, u16* __restrict__ dst, int i) {
  float4 a = *(const float4*)(src + i);
  float4 b = *(const float4*)(src + i + 4);
  u16x8 o;
  o[0]=f2bf(a.x); o[1]=f2bf(a.y); o[2]=f2bf(a.z); o[3]=f2bf(a.w);
  o[4]=f2bf(b.x); o[5]=f2bf(b.y); o[6]=f2bf(b.z); o[7]=f2bf(b.w);
  *(u16x8*)(dst + i) = o;
}

// blocks: [0,4096) X | [4096,5632) Wq/Wk/Wv (512 each) | [5632,5664) pad
__global__ void cvt_all(const float* __restrict__ X, const float* __restrict__ Wq,
                        const float* __restrict__ Wk, const float* __restrict__ Wv,
                        const int* __restrict__ pad,
                        u16* __restrict__ Xb, u16* __restrict__ Wb,
                        float* __restrict__ padf, u16* __restrict__ padb16) {
  const int bi = blockIdx.x;
  if (bi < 4096) {
    cvt8(X, Xb, bi*2048 + threadIdx.x*8);
  } else if (bi < 5632) {
    int r = bi - 4096;
    int mat = r >> 9, j = r & 511;
    const float* src = (mat == 0) ? Wq : (mat == 1) ? Wk : Wv;
    cvt8(src, Wb + (size_t)mat*E_*E_, j*2048 + threadIdx.x*8);
  } else {
    int i = (bi - 5632)*256 + threadIdx.x;
    float p = (float)pad[i];
    padf[i] = p;
    padb16[i] = f2bf(p);
  }
}

// ---------------- fused QKV projection GEMM ----------------
// 768 blocks x 512 threads. BM=256, BN=128, BK=32, 8 waves (4M x 2N), wave 64x64.
// 3-buffer (72 KB -> 2 blocks/CU), counted vmcnt(3), ONE s_barrier per K-step.
// LDS [.][32] rows (64B) XOR-swizzled with key l15&3 (both-sides, rule #21).
// mode 1 (V): output rows pre-multiplied by pad[kv].
__launch_bounds__(512)
__global__ void qkv_gemm3(const u16* __restrict__ A, const u16* __restrict__ Wall,
                          const float* __restrict__ bq, const float* __restrict__ bk,
                          const float* __restrict__ bv, const float* __restrict__ padf,
                          u16* __restrict__ Qb, u16* __restrict__ Kb, u16* __restrict__ Vtb,
                          float qscale) {
  __shared__ __align__(16) u16 As[3*256*32];   // 48 KB
  __shared__ __align__(16) u16 Bs[3*128*32];   // 24 KB
  const int t = threadIdx.x;        // 0..511
  const int lane = t & 63;
  const int w = t >> 6;             // wave 0..7
  const int wr = w >> 1, wc = w & 1;
  const int l15 = lane & 15, lhi = lane >> 4;
  const int l = blockIdx.x;
  const int xcd = l & 7, s = l >> 3;
  const int mat = s >> 5, inner = s & 31;
  const int m0 = (xcd*4 + (inner & 3)) * 256;
  const int n0 = (inner >> 2) * 128;
  const u16* W = Wall + (size_t)mat*E_*E_;
  const float* bias = (mat == 0) ? bq : (mat == 1) ? bk : bv;
  u16* out = (mat == 0) ? Qb : (mat == 1) ? Kb : Vtb;
  const float scale = (mat == 0) ? qscale : 1.0f;
  const int mode = (mat == 2);

  f32x4 acc[4][4] = {};

  // staging: thread t -> dest row = t>>2, col-blk = t&3 (8-elem blocks).
  // source col pre-swizzled: blk_src = (t&3) ^ ((t>>2)&3)
  const int rA = t >> 2;
  const int cbs = ((t & 3) ^ ((t >> 2) & 3)) * 8;
  const u16* Asrc = A + (size_t)(m0 + rA)*E_ + cbs;
  const u16* Wsrc = W + (size_t)(n0 + rA)*E_ + cbs;

  auto stage = [&](int bufi, int k0) {
    GLD16(Asrc + k0,                    As + bufi*8192 + t*8);
    GLD16(Asrc + (size_t)128*E_ + k0,   As + bufi*8192 + 4096 + t*8);
    GLD16(Wsrc + k0,                    Bs + bufi*4096 + t*8);
  };

  stage(0, 0);
  stage(1, 32);
  const int fkey = l15 & 3;
  const int arow = wr*64, brow = wc*64;
  int cur = 0, nxt = 1, nn = 2;
  for (int kt = 0; kt < 32; ++kt) {
    // counted vmcnt: tile kt's 3 loads retired; tile kt+1's stay in flight
    if (kt < 31) { asm volatile("s_waitcnt vmcnt(3)" ::: "memory"); }
    else         { asm volatile("s_waitcnt vmcnt(0)" ::: "memory"); }
    __builtin_amdgcn_s_barrier();
    __builtin_amdgcn_sched_barrier(0);
    const u16* Ab = As + cur*8192;
    const u16* Bb = Bs + cur*4096;
    bf16x8 af[4], bfr[4];
#pragma unroll
    for (int i = 0; i < 4; ++i)
      af[i] = *(const bf16x8*)&Ab[(arow + i*16 + l15)*32 + (lhi ^ fkey)*8];
#pragma unroll
    for (int i = 0; i < 4; ++i)
      bfr[i] = *(const bf16x8*)&Bb[(brow + i*16 + l15)*32 + (lhi ^ fkey)*8];
    if (kt + 2 < 32) stage(nn, (kt+2)*32);
    __builtin_amdgcn_s_setprio(1);
#pragma unroll
    for (int mi = 0; mi < 4; ++mi)
#pragma unroll
      for (int ni = 0; ni < 4; ++ni)
        acc[mi][ni] = __builtin_amdgcn_mfma_f32_16x16x32_bf16(af[mi], bfr[ni], acc[mi][ni], 0, 0, 0);
    __builtin_amdgcn_s_setprio(0);
    int tmp = cur; cur = nxt; nxt = nn; nn = tmp;
  }

  // epilogue (per-wave 64x64)
#pragma unroll
  for (int mi = 0; mi < 4; ++mi) {
#pragma unroll
    for (int ni = 0; ni < 4; ++ni) {
      int n = n0 + wc*64 + ni*16 + l15;
      float bia = bias[n];
      int h = n >> 6, d = n & 63;
      if (mode == 0) {
#pragma unroll
        for (int j = 0; j < 4; ++j) {
          int m = m0 + wr*64 + mi*16 + lhi*4 + j;
          int b = m >> 11, sq = m & 2047;
          out[((size_t)((b*H_ + h)*S_ + sq))*D_ + d] = f2bf((acc[mi][ni][j] + bia) * scale);
        }
      } else {
        int m = m0 + wr*64 + mi*16 + lhi*4;
        int b = m >> 11, sq = m & 2047;
        float4 pv = *(const float4*)(padf + b*S_ + sq);   // zero padded V rows
        u16 pk0 = f2bf((acc[mi][ni][0] + bia) * pv.x);
        u16 pk1 = f2bf((acc[mi][ni][1] + bia) * pv.y);
        u16 pk2 = f2bf((acc[mi][ni][2] + bia) * pv.z);
        u16 pk3 = f2bf((acc[mi][ni][3] + bia) * pv.w);
        u16* p = &out[((size_t)((b*H_ + h)*D_ + d))*S_ + sq];
        p[0]=pk0; p[1]=pk1; p[2]=pk2; p[3]=pk3;
      }
    }
  }
}

// ---------------- fused causal+pad flash attention (r12 verbatim) ----------------
// Q,K: [BH][S][D] bf16 (Q pre-scaled by log2e/sqrt(D)); Vt: [BH][D][S] bf16,
// V rows pre-zeroed at padded kv. Grid 512, paired halves (qt,15-qt), 8 waves,
// double-buffered K/V (48KB -> 3 blocks/CU). Pad folded out of inner loop.
#define QB 128
#define KB 64
#define NQT (S_/QB)   // 16
__launch_bounds__(512)
__global__ void attn(const u16* __restrict__ Q, const u16* __restrict__ Kg,
                     const u16* __restrict__ Vt, const float* __restrict__ padf,
                     const u16* __restrict__ padb16, float* __restrict__ out) {
  __shared__ __align__(16) u16 Ks[2*KB*64];   // 2 x [64 kv][64 d], swizzled
  __shared__ __align__(16) u16 Vs[2*64*KB];   // 2 x [64 d][64 kv], swizzled
  __shared__ __align__(16) u16 Ps[8*16*64];   // per-wave P [16 q][64 kv], swizzled
  const int t = threadIdx.x, lane = t & 63, w = t >> 6;   // w 0..7
  const int l15 = lane & 15, lhi = lane >> 4;
  const int l = blockIdx.x;                   // 512 blocks
  const int bh = (l & 7) + 8 * (l >> 6);
  const int xt = (l >> 3) & 7;                // q-tile pair index 0..7
  const int b = bh >> 4, h = bh & 15;
  const int lsw = ((lane >> 3) & 7) << 3;     // staging swizzle (elem units)
  const int key = l15 & 7;
  const int x0 = ((0 + lhi) ^ key) * 8;       // K/V fragment col offsets (elems)
  const int x1 = ((4 + lhi) ^ key) * 8;
  const int pw = w*1024 + l15*64;
  const int pxk = key << 4;
  int pwr[4], prd0, prd1;
#pragma unroll
  for (int f = 0; f < 4; ++f) pwr[f] = pw + (((f*32 + lhi*8) ^ pxk) >> 1);
  prd0 = pw + (((      lhi*16) ^ pxk) >> 1);
  prd1 = pw + (((64 +  lhi*16) ^ pxk) >> 1);

  const float* padb = padf + b*S_;
  const u16* padkb = padb16 + b*S_ + lhi*8;   // pad B-fragment base

  const int leo = (t*8) ^ lsw;
  const u16* Kls = Kg + (size_t)bh*S_*D_ + leo;
  const u16* Vls = Vt + (size_t)bh*D_*S_ + (size_t)(leo >> 6)*S_ + (leo & 63);
  u16* KsD = Ks + t*8;
  u16* VsD = Vs + t*8;

  for (int half = 0; half < 2; ++half) {
    const int qt = half ? (NQT - 1 - xt) : xt;
    const int q0 = qt * QB;
    const int nkt = 2*(qt + 1);

    const u16* Qrow = Q + (size_t)(bh*S_ + q0 + w*16 + l15)*D_;
    bf16x8 qa0 = *(const bf16x8*)(Qrow + lhi*8);
    bf16x8 qa1 = *(const bf16x8*)(Qrow + 32 + lhi*8);

    f32x4 o[4] = {};
    f32x4 ls = {};
    float mrow = -1e30f;

    GLD16(Kls, KsD);
    GLD16(Vls, VsD);
    __syncthreads();
    for (int kt = 0; kt < nkt; ++kt) {
      if (kt + 1 < nkt) {
        const int nb = (kt+1)&1, nkv = (kt+1)*KB;
        GLD16(Kls + nkv*D_, KsD + nb*4096);
        GLD16(Vls + nkv,    VsD + nb*4096);
      }
      const u16* Kb_ = Ks + (kt&1)*4096;
      const u16* Vb_ = Vs + (kt&1)*4096;
      const int kv0 = kt*KB;

      f32x4 sc[4];
      __builtin_amdgcn_s_setprio(1);
#pragma unroll
      for (int f = 0; f < 4; ++f) {
        const u16* kr = Kb_ + (f*16 + l15)*64;
        f32x4 z = {};
        z = __builtin_amdgcn_mfma_f32_16x16x32_bf16(*(const bf16x8*)(kr + x0), qa0, z, 0, 0, 0);
        z = __builtin_amdgcn_mfma_f32_16x16x32_bf16(*(const bf16x8*)(kr + x1), qa1, z, 0, 0, 0);
        sc[f] = z;
      }
      __builtin_amdgcn_s_setprio(0);
      if (kt >= nkt - 2) {
        const int rel = q0 + w*16 + l15 - kv0;
#pragma unroll
        for (int f = 0; f < 4; ++f)
#pragma unroll
          for (int j = 0; j < 4; ++j)
            if (f*16 + lhi*4 + j > rel) sc[f][j] = -1e30f;
      }
      float mx0 = fmaxf(fmaxf(sc[0][0], sc[0][1]), fmaxf(sc[0][2], sc[0][3]));
      float mx1 = fmaxf(fmaxf(sc[1][0], sc[1][1]), fmaxf(sc[1][2], sc[1][3]));
      float mx2 = fmaxf(fmaxf(sc[2][0], sc[2][1]), fmaxf(sc[2][2], sc[2][3]));
      float mx3 = fmaxf(fmaxf(sc[3][0], sc[3][1]), fmaxf(sc[3][2], sc[3][3]));
      float pmax = fmaxf(fmaxf(mx0, mx1), fmaxf(mx2, mx3));
      pmax = fmaxf(pmax, __shfl_xor(pmax, 16));
      pmax = fmaxf(pmax, __shfl_xor(pmax, 32));
      if (__any(pmax > mrow + 8.0f)) {
        float mnew = fmaxf(mrow, pmax);
        float corr = fexp2(mrow - mnew);
        mrow = mnew;
        float cr[4];
#pragma unroll
        for (int j = 0; j < 4; ++j) cr[j] = __shfl(corr, lhi*4 + j);
#pragma unroll
        for (int df = 0; df < 4; ++df)
#pragma unroll
          for (int j = 0; j < 4; ++j) o[df][j] *= cr[j];
#pragma unroll
        for (int j = 0; j < 4; ++j) ls[j] *= cr[j];
      }
      // exp2 + pack P (pad folded into ls-fragment / zeroed V)
#pragma unroll
      for (int f = 0; f < 4; ++f) {
        bf16x4 pk;
        pk[0] = (__bf16)fexp2(sc[f][0] - mrow);
        pk[1] = (__bf16)fexp2(sc[f][1] - mrow);
        pk[2] = (__bf16)fexp2(sc[f][2] - mrow);
        pk[3] = (__bf16)fexp2(sc[f][3] - mrow);
        *(bf16x4*)(Ps + pwr[f]) = pk;
      }
      bf16x8 pf0 = *(const bf16x8*)(padkb + kv0);
      bf16x8 pf1 = *(const bf16x8*)(padkb + kv0 + 32);
      bf16x8 pa0 = *(const bf16x8*)(Ps + prd0);
      bf16x8 pa1 = *(const bf16x8*)(Ps + prd1);
      __builtin_amdgcn_s_setprio(1);
      ls = __builtin_amdgcn_mfma_f32_16x16x32_bf16(pa0, pf0, ls, 0, 0, 0);
      ls = __builtin_amdgcn_mfma_f32_16x16x32_bf16(pa1, pf1, ls, 0, 0, 0);
#pragma unroll
      for (int df = 0; df < 4; ++df) {
        const u16* vr = Vb_ + (df*16 + l15)*64;
        o[df] = __builtin_amdgcn_mfma_f32_16x16x32_bf16(pa0, *(const bf16x8*)(vr + x0), o[df], 0, 0, 0);
        o[df] = __builtin_amdgcn_mfma_f32_16x16x32_bf16(pa1, *(const bf16x8*)(vr + x1), o[df], 0, 0, 0);
      }
      __builtin_amdgcn_s_setprio(0);
      __syncthreads();
    }

#pragma unroll
    for (int j = 0; j < 4; ++j) {
      int q = q0 + w*16 + lhi*4 + j;
      float lr = ls[j];
      float pq = padb[q];
      float inv = (lr > 0.f) ? pq / lr : 0.f;
#pragma unroll
      for (int df = 0; df < 4; ++df)
        out[((size_t)(b*S_ + q))*E_ + h*D_ + df*16 + l15] = o[df][j] * inv;
    }
  }
}

extern "C" void kernel_launch(void* const* d_in, const int* in_sizes, int n_in,
                              void* d_out, int out_size, void* d_ws, size_t ws_size,
                              hipStream_t stream) {
  const float* X  = (const float*)d_in[0];
  const int*  pad = (const int*)d_in[1];
  const float* Wq = (const float*)d_in[2];
  const float* bq = (const float*)d_in[3];
  const float* Wk = (const float*)d_in[4];
  const float* bk = (const float*)d_in[5];
  const float* Wv = (const float*)d_in[6];
  const float* bv = (const float*)d_in[7];
  float* out = (float*)d_out;

  u16* Xb  = (u16*)d_ws;                         // 16 MB
  u16* Wb  = Xb + (size_t)M_*E_;                 // 6 MB (3 matrices)
  u16* Qb  = Wb + (size_t)3*E_*E_;               // 16 MB
  u16* Kb  = Qb + (size_t)M_*E_;                 // 16 MB
  u16* Vtb = Kb + (size_t)M_*E_;                 // 16 MB
  float* padfb = (float*)(Vtb + (size_t)M_*E_);  // 32 KB
  u16* padb16 = (u16*)(padfb + B_*S_);           // 16 KB

  cvt_all<<<5664, 256, 0, stream>>>(X, Wq, Wk, Wv, pad, Xb, Wb, padfb, padb16);

  // Q pre-scaled by (1/sqrt(D)) * log2(e) so attention exp is pure exp2
  qkv_gemm3<<<768, 512, 0, stream>>>(Xb, Wb, bq, bk, bv, padfb, Qb, Kb, Vtb, 0.18033688f);

  attn<<<512, 512, 0, stream>>>(Qb, Kb, Vtb, padfb, padb16, out);
}

// Round 15
// 131.267 us; speedup vs baseline: 1.0915x; 1.0300x over previous
//
#include <hip/hip_runtime.h>
#include <stdint.h>

#define B_ 4
#define S_ 2048
#define E_ 1024
#define H_ 16
#define D_ 64
#define M_ (B_*S_)   // 8192

typedef unsigned short u16;
typedef __bf16 bf16x8 __attribute__((ext_vector_type(8)));
typedef __bf16 bf16x4 __attribute__((ext_vector_type(4)));
typedef float f32x4 __attribute__((ext_vector_type(4)));
typedef u16 u16x8 __attribute__((ext_vector_type(8)));

#define GLD16(g, l) __builtin_amdgcn_global_load_lds((const __attribute__((address_space(1))) void*)(g), (__attribute__((address_space(3))) void*)(l), 16, 0, 0)

__device__ inline float fexp2(float x) {
#if __has_builtin(__builtin_amdgcn_exp2f)
  return __builtin_amdgcn_exp2f(x);
#else
  return exp2f(x);
#endif
}

__device__ inline u16 f2bf(float f) {
  union { __bf16 b; u16 u; } cv; cv.b = (__bf16)f; return cv.u;
}

// ---------------- all converts in one launch ----------------
__device__ inline void cvt8(const float* __restrict__ src, u16* __restrict__ dst, int i) {
  float4 a = *(const float4*)(src + i);
  float4 b = *(const float4*)(src + i + 4);
  u16x8 o;
  o[0]=f2bf(a.x); o[1]=f2bf(a.y); o[2]=f2bf(a.z); o[3]=f2bf(a.w);
  o[4]=f2bf(b.x); o[5]=f2bf(b.y); o[6]=f2bf(b.z); o[7]=f2bf(b.w);
  *(u16x8*)(dst + i) = o;
}

// blocks: [0,4096) X | [4096,5632) Wq/Wk/Wv (512 each) | [5632,5664) pad
__global__ void cvt_all(const float* __restrict__ X, const float* __restrict__ Wq,
                        const float* __restrict__ Wk, const float* __restrict__ Wv,
                        const int* __restrict__ pad,
                        u16* __restrict__ Xb, u16* __restrict__ Wb,
                        float* __restrict__ padf, u16* __restrict__ padb16) {
  const int bi = blockIdx.x;
  if (bi < 4096) {
    cvt8(X, Xb, bi*2048 + threadIdx.x*8);
  } else if (bi < 5632) {
    int r = bi - 4096;
    int mat = r >> 9, j = r & 511;
    const float* src = (mat == 0) ? Wq : (mat == 1) ? Wk : Wv;
    cvt8(src, Wb + (size_t)mat*E_*E_, j*2048 + threadIdx.x*8);
  } else {
    int i = (bi - 5632)*256 + threadIdx.x;
    float p = (float)pad[i];
    padf[i] = p;
    padb16[i] = f2bf(p);
  }
}

// ---------------- fused QKV projection GEMM (unchanged from round 14) ----------------
// 768 blocks x 512 threads. BM=256, BN=128, BK=32, 8 waves (4M x 2N), wave 64x64.
// 3-buffer (72 KB -> 2 blocks/CU), counted vmcnt(3), ONE s_barrier per K-step.
__launch_bounds__(512)
__global__ void qkv_gemm3(const u16* __restrict__ A, const u16* __restrict__ Wall,
                          const float* __restrict__ bq, const float* __restrict__ bk,
                          const float* __restrict__ bv, const float* __restrict__ padf,
                          u16* __restrict__ Qb, u16* __restrict__ Kb, u16* __restrict__ Vtb,
                          float qscale) {
  __shared__ __align__(16) u16 As[3*256*32];   // 48 KB
  __shared__ __align__(16) u16 Bs[3*128*32];   // 24 KB
  const int t = threadIdx.x;        // 0..511
  const int lane = t & 63;
  const int w = t >> 6;             // wave 0..7
  const int wr = w >> 1, wc = w & 1;
  const int l15 = lane & 15, lhi = lane >> 4;
  const int l = blockIdx.x;
  const int xcd = l & 7, s = l >> 3;
  const int mat = s >> 5, inner = s & 31;
  const int m0 = (xcd*4 + (inner & 3)) * 256;
  const int n0 = (inner >> 2) * 128;
  const u16* W = Wall + (size_t)mat*E_*E_;
  const float* bias = (mat == 0) ? bq : (mat == 1) ? bk : bv;
  u16* out = (mat == 0) ? Qb : (mat == 1) ? Kb : Vtb;
  const float scale = (mat == 0) ? qscale : 1.0f;
  const int mode = (mat == 2);

  f32x4 acc[4][4] = {};

  const int rA = t >> 2;
  const int cbs = ((t & 3) ^ ((t >> 2) & 3)) * 8;
  const u16* Asrc = A + (size_t)(m0 + rA)*E_ + cbs;
  const u16* Wsrc = W + (size_t)(n0 + rA)*E_ + cbs;

  auto stage = [&](int bufi, int k0) {
    GLD16(Asrc + k0,                    As + bufi*8192 + t*8);
    GLD16(Asrc + (size_t)128*E_ + k0,   As + bufi*8192 + 4096 + t*8);
    GLD16(Wsrc + k0,                    Bs + bufi*4096 + t*8);
  };

  stage(0, 0);
  stage(1, 32);
  const int fkey = l15 & 3;
  const int arow = wr*64, brow = wc*64;
  int cur = 0, nxt = 1, nn = 2;
  for (int kt = 0; kt < 32; ++kt) {
    if (kt < 31) { asm volatile("s_waitcnt vmcnt(3)" ::: "memory"); }
    else         { asm volatile("s_waitcnt vmcnt(0)" ::: "memory"); }
    __builtin_amdgcn_s_barrier();
    __builtin_amdgcn_sched_barrier(0);
    const u16* Ab = As + cur*8192;
    const u16* Bb = Bs + cur*4096;
    bf16x8 af[4], bfr[4];
#pragma unroll
    for (int i = 0; i < 4; ++i)
      af[i] = *(const bf16x8*)&Ab[(arow + i*16 + l15)*32 + (lhi ^ fkey)*8];
#pragma unroll
    for (int i = 0; i < 4; ++i)
      bfr[i] = *(const bf16x8*)&Bb[(brow + i*16 + l15)*32 + (lhi ^ fkey)*8];
    if (kt + 2 < 32) stage(nn, (kt+2)*32);
    __builtin_amdgcn_s_setprio(1);
#pragma unroll
    for (int mi = 0; mi < 4; ++mi)
#pragma unroll
      for (int ni = 0; ni < 4; ++ni)
        acc[mi][ni] = __builtin_amdgcn_mfma_f32_16x16x32_bf16(af[mi], bfr[ni], acc[mi][ni], 0, 0, 0);
    __builtin_amdgcn_s_setprio(0);
    int tmp = cur; cur = nxt; nxt = nn; nn = tmp;
  }

  // epilogue (per-wave 64x64)
#pragma unroll
  for (int mi = 0; mi < 4; ++mi) {
#pragma unroll
    for (int ni = 0; ni < 4; ++ni) {
      int n = n0 + wc*64 + ni*16 + l15;
      float bia = bias[n];
      int h = n >> 6, d = n & 63;
      if (mode == 0) {
#pragma unroll
        for (int j = 0; j < 4; ++j) {
          int m = m0 + wr*64 + mi*16 + lhi*4 + j;
          int b = m >> 11, sq = m & 2047;
          out[((size_t)((b*H_ + h)*S_ + sq))*D_ + d] = f2bf((acc[mi][ni][j] + bia) * scale);
        }
      } else {
        int m = m0 + wr*64 + mi*16 + lhi*4;
        int b = m >> 11, sq = m & 2047;
        float4 pv = *(const float4*)(padf + b*S_ + sq);   // zero padded V rows
        u16 pk0 = f2bf((acc[mi][ni][0] + bia) * pv.x);
        u16 pk1 = f2bf((acc[mi][ni][1] + bia) * pv.y);
        u16 pk2 = f2bf((acc[mi][ni][2] + bia) * pv.z);
        u16 pk3 = f2bf((acc[mi][ni][3] + bia) * pv.w);
        u16* p = &out[((size_t)((b*H_ + h)*D_ + d))*S_ + sq];
        p[0]=pk0; p[1]=pk1; p[2]=pk2; p[3]=pk3;
      }
    }
  }
}

// ---------------- fused causal+pad flash attention ----------------
// r12 structure + fully-deferred max: steady-state tile does NO cross-lane
// shuffles (per-lane max + __any test only); the full reduce+rescale runs
// only when some element exceeds mrow+8 (first tile, then rare). Invariant:
// every P element <= 2^8 -- bf16-safe; mrow stays consistent per row since
// updates happen only in the fully-reduced path.
#define QB 128
#define KB 64
#define NQT (S_/QB)   // 16
__launch_bounds__(512)
__global__ void attn(const u16* __restrict__ Q, const u16* __restrict__ Kg,
                     const u16* __restrict__ Vt, const float* __restrict__ padf,
                     const u16* __restrict__ padb16, float* __restrict__ out) {
  __shared__ __align__(16) u16 Ks[2*KB*64];   // 2 x [64 kv][64 d], swizzled
  __shared__ __align__(16) u16 Vs[2*64*KB];   // 2 x [64 d][64 kv], swizzled
  __shared__ __align__(16) u16 Ps[8*16*64];   // per-wave P [16 q][64 kv], swizzled
  const int t = threadIdx.x, lane = t & 63, w = t >> 6;   // w 0..7
  const int l15 = lane & 15, lhi = lane >> 4;
  const int l = blockIdx.x;                   // 512 blocks
  const int bh = (l & 7) + 8 * (l >> 6);
  const int xt = (l >> 3) & 7;                // q-tile pair index 0..7
  const int b = bh >> 4, h = bh & 15;
  const int lsw = ((lane >> 3) & 7) << 3;     // staging swizzle (elem units)
  const int key = l15 & 7;
  const int x0 = ((0 + lhi) ^ key) * 8;       // K/V fragment col offsets (elems)
  const int x1 = ((4 + lhi) ^ key) * 8;
  const int pw = w*1024 + l15*64;
  const int pxk = key << 4;
  int pwr[4], prd0, prd1;
#pragma unroll
  for (int f = 0; f < 4; ++f) pwr[f] = pw + (((f*32 + lhi*8) ^ pxk) >> 1);
  prd0 = pw + (((      lhi*16) ^ pxk) >> 1);
  prd1 = pw + (((64 +  lhi*16) ^ pxk) >> 1);

  const float* padb = padf + b*S_;
  const u16* padkb = padb16 + b*S_ + lhi*8;   // pad B-fragment base

  const int leo = (t*8) ^ lsw;
  const u16* Kls = Kg + (size_t)bh*S_*D_ + leo;
  const u16* Vls = Vt + (size_t)bh*D_*S_ + (size_t)(leo >> 6)*S_ + (leo & 63);
  u16* KsD = Ks + t*8;
  u16* VsD = Vs + t*8;

  for (int half = 0; half < 2; ++half) {
    const int qt = half ? (NQT - 1 - xt) : xt;
    const int q0 = qt * QB;
    const int nkt = 2*(qt + 1);

    const u16* Qrow = Q + (size_t)(bh*S_ + q0 + w*16 + l15)*D_;
    bf16x8 qa0 = *(const bf16x8*)(Qrow + lhi*8);
    bf16x8 qa1 = *(const bf16x8*)(Qrow + 32 + lhi*8);

    f32x4 o[4] = {};
    f32x4 ls = {};
    float mrow = -1e30f;

    GLD16(Kls, KsD);
    GLD16(Vls, VsD);
    __syncthreads();
    for (int kt = 0; kt < nkt; ++kt) {
      if (kt + 1 < nkt) {
        const int nb = (kt+1)&1, nkv = (kt+1)*KB;
        GLD16(Kls + nkv*D_, KsD + nb*4096);
        GLD16(Vls + nkv,    VsD + nb*4096);
      }
      const u16* Kb_ = Ks + (kt&1)*4096;
      const u16* Vb_ = Vs + (kt&1)*4096;
      const int kv0 = kt*KB;

      f32x4 sc[4];
      __builtin_amdgcn_s_setprio(1);
#pragma unroll
      for (int f = 0; f < 4; ++f) {
        const u16* kr = Kb_ + (f*16 + l15)*64;
        f32x4 z = {};
        z = __builtin_amdgcn_mfma_f32_16x16x32_bf16(*(const bf16x8*)(kr + x0), qa0, z, 0, 0, 0);
        z = __builtin_amdgcn_mfma_f32_16x16x32_bf16(*(const bf16x8*)(kr + x1), qa1, z, 0, 0, 0);
        sc[f] = z;
      }
      __builtin_amdgcn_s_setprio(0);
      if (kt >= nkt - 2) {
        const int rel = q0 + w*16 + l15 - kv0;
#pragma unroll
        for (int f = 0; f < 4; ++f)
#pragma unroll
          for (int j = 0; j < 4; ++j)
            if (f*16 + lhi*4 + j > rel) sc[f][j] = -1e30f;
      }
      // per-lane max only (max3-friendly triples); no cross-lane shuffles
      // in the steady state
      float t0 = fmaxf(fmaxf(sc[0][0], sc[0][1]), sc[0][2]);
      float t1 = fmaxf(fmaxf(sc[0][3], sc[1][0]), sc[1][1]);
      float t2 = fmaxf(fmaxf(sc[1][2], sc[1][3]), sc[2][0]);
      float t3 = fmaxf(fmaxf(sc[2][1], sc[2][2]), sc[2][3]);
      float t4 = fmaxf(fmaxf(sc[3][0], sc[3][1]), sc[3][2]);
      float lmax = fmaxf(fmaxf(fmaxf(t0, t1), fmaxf(t2, t3)),
                         fmaxf(t4, sc[3][3]));
      // fully-deferred max: reduce + rescale only when the bound is violated
      if (__any(lmax > mrow + 8.0f)) {
        float pmax = fmaxf(lmax, __shfl_xor(lmax, 16));
        pmax = fmaxf(pmax, __shfl_xor(pmax, 32));
        float mnew = fmaxf(mrow, pmax);
        float corr = fexp2(mrow - mnew);
        mrow = mnew;
        float cr[4];
#pragma unroll
        for (int j = 0; j < 4; ++j) cr[j] = __shfl(corr, lhi*4 + j);
#pragma unroll
        for (int df = 0; df < 4; ++df)
#pragma unroll
          for (int j = 0; j < 4; ++j) o[df][j] *= cr[j];
#pragma unroll
        for (int j = 0; j < 4; ++j) ls[j] *= cr[j];
      }
      // exp2 + pack P (pad folded into ls-fragment / zeroed V)
#pragma unroll
      for (int f = 0; f < 4; ++f) {
        bf16x4 pk;
        pk[0] = (__bf16)fexp2(sc[f][0] - mrow);
        pk[1] = (__bf16)fexp2(sc[f][1] - mrow);
        pk[2] = (__bf16)fexp2(sc[f][2] - mrow);
        pk[3] = (__bf16)fexp2(sc[f][3] - mrow);
        *(bf16x4*)(Ps + pwr[f]) = pk;
      }
      bf16x8 pf0 = *(const bf16x8*)(padkb + kv0);
      bf16x8 pf1 = *(const bf16x8*)(padkb + kv0 + 32);
      bf16x8 pa0 = *(const bf16x8*)(Ps + prd0);
      bf16x8 pa1 = *(const bf16x8*)(Ps + prd1);
      __builtin_amdgcn_s_setprio(1);
      ls = __builtin_amdgcn_mfma_f32_16x16x32_bf16(pa0, pf0, ls, 0, 0, 0);
      ls = __builtin_amdgcn_mfma_f32_16x16x32_bf16(pa1, pf1, ls, 0, 0, 0);
#pragma unroll
      for (int df = 0; df < 4; ++df) {
        const u16* vr = Vb_ + (df*16 + l15)*64;
        o[df] = __builtin_amdgcn_mfma_f32_16x16x32_bf16(pa0, *(const bf16x8*)(vr + x0), o[df], 0, 0, 0);
        o[df] = __builtin_amdgcn_mfma_f32_16x16x32_bf16(pa1, *(const bf16x8*)(vr + x1), o[df], 0, 0, 0);
      }
      __builtin_amdgcn_s_setprio(0);
      __syncthreads();
    }

#pragma unroll
    for (int j = 0; j < 4; ++j) {
      int q = q0 + w*16 + lhi*4 + j;
      float lr = ls[j];
      float pq = padb[q];
      float inv = (lr > 0.f) ? pq / lr : 0.f;
#pragma unroll
      for (int df = 0; df < 4; ++df)
        out[((size_t)(b*S_ + q))*E_ + h*D_ + df*16 + l15] = o[df][j] * inv;
    }
  }
}

extern "C" void kernel_launch(void* const* d_in, const int* in_sizes, int n_in,
                              void* d_out, int out_size, void* d_ws, size_t ws_size,
                              hipStream_t stream) {
  const float* X  = (const float*)d_in[0];
  const int*  pad = (const int*)d_in[1];
  const float* Wq = (const float*)d_in[2];
  const float* bq = (const float*)d_in[3];
  const float* Wk = (const float*)d_in[4];
  const float* bk = (const float*)d_in[5];
  const float* Wv = (const float*)d_in[6];
  const float* bv = (const float*)d_in[7];
  float* out = (float*)d_out;

  u16* Xb  = (u16*)d_ws;                         // 16 MB
  u16* Wb  = Xb + (size_t)M_*E_;                 // 6 MB (3 matrices)
  u16* Qb  = Wb + (size_t)3*E_*E_;               // 16 MB
  u16* Kb  = Qb + (size_t)M_*E_;                 // 16 MB
  u16* Vtb = Kb + (size_t)M_*E_;                 // 16 MB
  float* padfb = (float*)(Vtb + (size_t)M_*E_);  // 32 KB
  u16* padb16 = (u16*)(padfb + B_*S_);           // 16 KB

  cvt_all<<<5664, 256, 0, stream>>>(X, Wq, Wk, Wv, pad, Xb, Wb, padfb, padb16);

  // Q pre-scaled by (1/sqrt(D)) * log2(e) so attention exp is pure exp2
  qkv_gemm3<<<768, 512, 0, stream>>>(Xb, Wb, bq, bk, bv, padfb, Qb, Kb, Vtb, 0.18033688f);

  attn<<<512, 512, 0, stream>>>(Qb, Kb, Vtb, padfb, padb16, out);
}